// Round 9
// baseline (217.427 us; speedup 1.0000x reference)
//
#include <hip/hip_runtime.h>

// ZNCC fused streaming kernel. [16,3,512,512] f32 -> [16,1,512,512] f32.
// 5x5 box means, zero pad, /25 everywhere; second box over centered products.
//
// Structure: 1-wave blocks, block=(b,ch,seg,strip); rows staged ONCE into an
// LDS ring via a 2-deep REGISTER queue (all load->use deps are plain C++
// dataflow -> compiler emits exact counted vmcnt; no inferred-wait hazards);
// 3 consumes per row (add/center/subtract) are ds_reads.
// R7: f32 ring RING=9 (DMA prefetch in-ring) = 19.4KB -> 8 blocks/CU, 97us.
// R8: f16 ring RING=6 + reg queue = 6.3KB, 73us — but the f16 pack/unpack
//     tax was ~40% of VALU (~200 ops/iter), bought LDS headroom the 12
//     blocks/CU grid can't use.
// R9: f32 ring RING=6 = 12.7KB. LDS cap = floor(160/12.7) = 12 blocks/CU =
//     exactly the grid supply, so residency is unchanged while ALL f16
//     conversion VALU disappears (ds_write_b128/ds_read_b128 straight f32).
//     Also removes the f16 precision loss (absmax back to ~2e-3).

constexpr int W = 512, H = 512, Cn = 3, Bn = 16;
constexpr int HS = 16;        // output rows per segment
constexpr int NITER = HS + 8; // 24
constexpr int RING = 6;       // rows L-5..L live in LDS
constexpr int CHUNKS = 66;    // quad 0 = left halo, 1..64 main, 65 = right halo
constexpr int STRIPW = 256;
constexpr int NSEG = H / HS;  // 32

__device__ __forceinline__ void pin() {
    asm volatile("" ::: "memory");
    __builtin_amdgcn_sched_barrier(0);
}

__device__ __forceinline__ void unpack12f(const float4* slot, int lane, float* d) {
    float4 a = slot[lane];
    float4 b = slot[lane + 1];
    float4 c = slot[lane + 2];
    d[0]=a.x; d[1]=a.y; d[2] =a.z; d[3] =a.w;
    d[4]=b.x; d[5]=b.y; d[6] =b.z; d[7] =b.w;
    d[8]=c.x; d[9]=c.y; d[10]=c.z; d[11]=c.w;
}

template <bool ATOMIC>
__global__ __launch_bounds__(64) void zncc_stream(const float* __restrict__ xg,
                                                  const float* __restrict__ yg,
                                                  float* __restrict__ outg) {
    __shared__ float4 ring[2][RING][CHUNKS];   // 2*6*66*16 = 12672 B

    const int lane  = threadIdx.x;        // 0..63
    const int strip = blockIdx.x & 1;
    const int seg   = blockIdx.x >> 1;    // 0..31
    const int b     = blockIdx.y;
    const int ch    = blockIdx.z;
    const int o0    = seg * HS;

    const float* __restrict__ xp = xg + ((size_t)(b * Cn + ch)) * (H * W);
    const float* __restrict__ yp = yg + ((size_t)(b * Cn + ch)) * (H * W);
    float* __restrict__ outp =
        ATOMIC ? outg + (size_t)b * (H * W) + strip * STRIPW + lane * 4
               : outg + ((size_t)(b * Cn + ch)) * (H * W) + strip * STRIPW + lane * 4;

    const int m0 = strip * STRIPW + lane * 4;     // first output col
    // column-edge masks: only lane0/strip0 (left) and lane63/strip1 (right) clamp
    const float mA = (strip == 0 && lane == 0)  ? 0.f : 1.f;
    const float mC = (strip == 1 && lane == 63) ? 0.f : 1.f;

    float pm[8];
#pragma unroll
    for (int i = 0; i < 8; ++i) {
        int col = m0 - 2 + i;
        pm[i] = (col >= 0 && col < W) ? 1.f : 0.f;
    }

    // staging addresses
    const int sMain = strip * STRIPW + lane * 4;             // main quad src elem
    const int hoff  = lane ? (strip ? 508 : 256)             // right halo src
                           : (strip ? 252 : 0);              // left  halo src (clamped)
    const int hIdx  = lane ? 65 : 0;                         // halo quad in slot
    const bool hal  = lane < 2;

    // 2-deep register staging queue (rows L+1, L+2 in flight)
    float4 qmx[2], qmy[2], qhx[2], qhy[2];

    // prologue: load rows o0-4, o0-3 (clamped low) into queue slots 0,1
#pragma unroll
    for (int p = 0; p < 2; ++p) {
        const int rp = o0 - 4 + p;
        const int rc = rp < 0 ? 0 : rp;          // rp <= 494, no upper clamp
        const float* xr = xp + (size_t)rc * W;
        const float* yr = yp + (size_t)rc * W;
        qmx[p] = *(const float4*)(xr + sMain);
        qmy[p] = *(const float4*)(yr + sMain);
        if (hal) {
            qhx[p] = *(const float4*)(xr + hoff);
            qhy[p] = *(const float4*)(yr + hoff);
        }
    }

    float vsx[12], vsy[12];
    float qxx[5][4], qxy[5][4], qyy[5][4];
    float oxx[4], oxy[4], oyy[4];
#pragma unroll
    for (int i = 0; i < 12; ++i) { vsx[i] = 0.f; vsy[i] = 0.f; }
#pragma unroll
    for (int s = 0; s < 5; ++s)
#pragma unroll
        for (int j = 0; j < 4; ++j) { qxx[s][j] = 0.f; qxy[s][j] = 0.f; qyy[s][j] = 0.f; }
#pragma unroll
    for (int j = 0; j < 4; ++j) { oxx[j] = 0.f; oxy[j] = 0.f; oyy[j] = 0.f; }

    // iter k: row L = o0-4+k; queue slot k&1 holds row L (loaded at iter k-2 /
    // prologue); LDS slot k%6 receives row L this iter. vsum rows L-4..L;
    // products at V=L-2 (k>=4, slot (k-2)%6); subtract L-5 (k>=5, slot (k-5)%6,
    // freed right before iter k+1 overwrites it); output row o0+k-8 (k>=8).
#pragma unroll
    for (int k = 0; k < NITER; ++k) {
        const int L  = o0 - 4 + k;
        const int sL = k % RING;
        const int qs = k & 1;

        // (1) ds_write row L from reg queue (compiler emits the counted vmcnt
        //     for the loads issued 2 iters ago — exact by dataflow, leaves
        //     iter k-1's loads in flight)
        ring[0][sL][lane + 1] = qmx[qs];
        ring[1][sL][lane + 1] = qmy[qs];
        if (hal) {
            ring[0][sL][hIdx] = qhx[qs];
            ring[1][sL][hIdx] = qhy[qs];
        }

        // (2) refill queue slot with row L+2 (clamped), issued before consume
        if (k < NITER - 2) {
            int rn = L + 2; rn = rn < 0 ? 0 : (rn > H - 1 ? H - 1 : rn);
            const float* xr = xp + (size_t)rn * W;
            const float* yr = yp + (size_t)rn * W;
            qmx[qs] = *(const float4*)(xr + sMain);
            qmy[qs] = *(const float4*)(yr + sMain);
            if (hal) {
                qhx[qs] = *(const float4*)(xr + hoff);
                qhy[qs] = *(const float4*)(yr + hoff);
            }
        }
        pin();   // keep the refill loads issued ahead of the consume block

        // (3) consume — row guards are branchless scalar 0/1 masks
        // add row L
        {
            const float rmN = (L >= 0 && L < H) ? 1.f : 0.f;
            const float cA = mA * rmN, cC = mC * rmN;
            float nx[12], ny[12];
            unpack12f(&ring[0][sL][0], lane, nx);
            unpack12f(&ring[1][sL][0], lane, ny);
            vsx[0] = fmaf(nx[0], rmN, vsx[0]); vsx[1] = fmaf(nx[1], rmN, vsx[1]);
            vsx[2] = fmaf(nx[2], cA,  vsx[2]); vsx[3] = fmaf(nx[3], cA,  vsx[3]);
#pragma unroll
            for (int i = 4; i < 8; ++i) vsx[i] = fmaf(nx[i], rmN, vsx[i]);
            vsx[8] = fmaf(nx[8], cC, vsx[8]); vsx[9] = fmaf(nx[9], cC, vsx[9]);
            vsx[10] = fmaf(nx[10], rmN, vsx[10]); vsx[11] = fmaf(nx[11], rmN, vsx[11]);

            vsy[0] = fmaf(ny[0], rmN, vsy[0]); vsy[1] = fmaf(ny[1], rmN, vsy[1]);
            vsy[2] = fmaf(ny[2], cA,  vsy[2]); vsy[3] = fmaf(ny[3], cA,  vsy[3]);
#pragma unroll
            for (int i = 4; i < 8; ++i) vsy[i] = fmaf(ny[i], rmN, vsy[i]);
            vsy[8] = fmaf(ny[8], cC, vsy[8]); vsy[9] = fmaf(ny[9], cC, vsy[9]);
            vsy[10] = fmaf(ny[10], rmN, vsy[10]); vsy[11] = fmaf(ny[11], rmN, vsy[11]);
        }

        // subtract row L-5 (added at iter k-5; slot freed for iter k+1)
        if (k >= 5) {
            const int Lo = L - 5;
            const float rmO = (Lo >= 0) ? -1.f : 0.f;
            const float cA = mA * rmO, cC = mC * rmO;
            const int sO = (k - 5) % RING;
            float ox[12], oy[12];
            unpack12f(&ring[0][sO][0], lane, ox);
            unpack12f(&ring[1][sO][0], lane, oy);
            vsx[0] = fmaf(ox[0], rmO, vsx[0]); vsx[1] = fmaf(ox[1], rmO, vsx[1]);
            vsx[2] = fmaf(ox[2], cA,  vsx[2]); vsx[3] = fmaf(ox[3], cA,  vsx[3]);
#pragma unroll
            for (int i = 4; i < 8; ++i) vsx[i] = fmaf(ox[i], rmO, vsx[i]);
            vsx[8] = fmaf(ox[8], cC, vsx[8]); vsx[9] = fmaf(ox[9], cC, vsx[9]);
            vsx[10] = fmaf(ox[10], rmO, vsx[10]); vsx[11] = fmaf(ox[11], rmO, vsx[11]);

            vsy[0] = fmaf(oy[0], rmO, vsy[0]); vsy[1] = fmaf(oy[1], rmO, vsy[1]);
            vsy[2] = fmaf(oy[2], cA,  vsy[2]); vsy[3] = fmaf(oy[3], cA,  vsy[3]);
#pragma unroll
            for (int i = 4; i < 8; ++i) vsy[i] = fmaf(oy[i], rmO, vsy[i]);
            vsy[8] = fmaf(oy[8], cC, vsy[8]); vsy[9] = fmaf(oy[9], cC, vsy[9]);
            vsy[10] = fmaf(oy[10], rmO, vsy[10]); vsy[11] = fmaf(oy[11], rmO, vsy[11]);
        }

        if (k >= 4) {
            const int u = k % 5;   // hp queue slot (static after unroll)
#pragma unroll
            for (int j = 0; j < 4; ++j) {
                oxx[j] -= qxx[u][j]; oxy[j] -= qxy[u][j]; oyy[j] -= qyy[u][j];
            }
            const int V  = L - 2;
            const int sV = (k - 2) % RING;
            if (V >= 0 && V < H) {
                float mx[8], my[8];
                mx[0] = vsx[0] + vsx[1] + vsx[2] + vsx[3] + vsx[4];
                my[0] = vsy[0] + vsy[1] + vsy[2] + vsy[3] + vsy[4];
#pragma unroll
                for (int i = 1; i < 8; ++i) {
                    mx[i] = mx[i - 1] - vsx[i - 1] + vsx[i + 4];
                    my[i] = my[i - 1] - vsy[i - 1] + vsy[i + 4];
                }
                float cx[12], cyv[12];
                unpack12f(&ring[0][sV][0], lane, cx);
                unpack12f(&ring[1][sV][0], lane, cyv);

                float pxx[8], pxy[8], pyy[8];
#pragma unroll
                for (int i = 0; i < 8; ++i) {
                    float xc = (cx[i + 2]  - mx[i] * 0.04f) * pm[i];
                    float yc = (cyv[i + 2] - my[i] * 0.04f) * pm[i];
                    pxx[i] = xc * xc; pxy[i] = xc * yc; pyy[i] = yc * yc;
                }
                float h;
                h = pxx[0] + pxx[1] + pxx[2] + pxx[3] + pxx[4];
                qxx[u][0] = h; oxx[0] += h;
#pragma unroll
                for (int j = 1; j < 4; ++j) {
                    h = h - pxx[j - 1] + pxx[j + 4]; qxx[u][j] = h; oxx[j] += h;
                }
                h = pxy[0] + pxy[1] + pxy[2] + pxy[3] + pxy[4];
                qxy[u][0] = h; oxy[0] += h;
#pragma unroll
                for (int j = 1; j < 4; ++j) {
                    h = h - pxy[j - 1] + pxy[j + 4]; qxy[u][j] = h; oxy[j] += h;
                }
                h = pyy[0] + pyy[1] + pyy[2] + pyy[3] + pyy[4];
                qyy[u][0] = h; oyy[0] += h;
#pragma unroll
                for (int j = 1; j < 4; ++j) {
                    h = h - pyy[j - 1] + pyy[j + 4]; qyy[u][j] = h; oyy[j] += h;
                }
            } else {
                // padding row: products are zero
#pragma unroll
                for (int j = 0; j < 4; ++j) { qxx[u][j] = 0.f; qxy[u][j] = 0.f; qyy[u][j] = 0.f; }
            }

            if (k >= 8) {
                const int row = o0 + k - 8;
                float r[4];
#pragma unroll
                for (int j = 0; j < 4; ++j) {
                    // ncc = Sxy / (sqrt(Sxx*Syy) + 25e-8)
                    float rad = fmaxf(oxx[j] * oyy[j], 0.f);
                    float s = sqrtf(rad) + 2.5e-7f;
                    r[j] = oxy[j] * __builtin_amdgcn_rcpf(s);
                }
                if (ATOMIC) {
#pragma unroll
                    for (int j = 0; j < 4; ++j)
                        atomicAdd(outp + (size_t)row * W + j, r[j] * (1.f / 3.f));
                } else {
                    *(float4*)(outp + (size_t)row * W) =
                        make_float4(r[0], r[1], r[2], r[3]);
                }
            }
        }
    }
}

// out = (ch0 + ch1 + ch2) / 3 over the workspace planes
__global__ __launch_bounds__(256) void reduce3(const float4* __restrict__ ws,
                                               float4* __restrict__ o) {
    constexpr int PLANE4 = H * W / 4;           // 65536 float4 per plane
    constexpr int N4 = Bn * PLANE4;             // 1048576
    const float s = 1.f / 3.f;
    for (int g = blockIdx.x * 256 + threadIdx.x; g < N4; g += gridDim.x * 256) {
        const int bq = g >> 16;                 // PLANE4 == 1<<16
        const int r  = g & (PLANE4 - 1);
        const float4* p = ws + ((size_t)bq * 3) * PLANE4 + r;
        float4 a = p[0], c = p[PLANE4], d = p[2 * PLANE4];
        float4 v;
        v.x = (a.x + c.x + d.x) * s;
        v.y = (a.y + c.y + d.y) * s;
        v.z = (a.z + c.z + d.z) * s;
        v.w = (a.w + c.w + d.w) * s;
        o[g] = v;
    }
}

extern "C" void kernel_launch(void* const* d_in, const int* in_sizes, int n_in,
                              void* d_out, int out_size, void* d_ws, size_t ws_size,
                              hipStream_t stream) {
    const float* x = (const float*)d_in[0];
    const float* y = (const float*)d_in[1];
    float* out = (float*)d_out;
    dim3 grid(2 * NSEG, Bn, Cn);   // 64 x 16 x 3 = 3072 one-wave blocks

    const size_t needed = (size_t)Bn * Cn * H * W * sizeof(float);  // 50.3 MB
    if (d_ws != nullptr && ws_size >= needed) {
        zncc_stream<false><<<grid, 64, 0, stream>>>(x, y, (float*)d_ws);
        reduce3<<<2048, 256, 0, stream>>>((const float4*)d_ws, (float4*)out);
    } else {
        // harness pre-zeroes the output buffer; atomics accumulate on top
        zncc_stream<true><<<grid, 64, 0, stream>>>(x, y, out);
    }
}

// Round 11
// 152.038 us; speedup vs baseline: 1.4301x; 1.4301x over previous
//
#include <hip/hip_runtime.h>
#include <hip/hip_fp16.h>

// ZNCC fused streaming kernel. [16,3,512,512] f32 -> [16,1,512,512] f32.
// 5x5 box means, zero pad, /25 everywhere; second box over centered products.
//
// Structure: 1-wave blocks, block=(b,ch,seg,strip); rows staged ONCE into an
// f16 LDS ring (RING=6) via a REGISTER queue (all load->use deps are plain
// C++ dataflow -> compiler emits exact counted vmcnt; no inferred-wait
// hazards); 3 consumes per row (add/center/subtract) are ds_reads.
// R8 (f16 ring, depth-2 queue): 73us main, VALUBusy 43%, per-wave duty ~15%
//     -> still latency-bound on the refill vmcnt.
// R9 (f32 ring): compiler demoted float4 ring temps to scratch (VGPR 84,
//     WRITE 213MB) -> 120us. f16/uint2 is the codegen-safe shape; reverted.
// R10: R8 + (a) queue depth 3; (b) cvt_pkrtz pack / __half22float2 unpack;
//     (c) consume batches all slot ds_reads before converting.
//     Failed to compile: cvt_pkrtz returns __fp16 ext_vector(2), not
//     _Float16 vector. R11: take it as auto + bit_cast. No other change.

constexpr int W = 512, H = 512, Cn = 3, Bn = 16;
constexpr int HS = 16;        // output rows per segment
constexpr int NITER = HS + 8; // 24
constexpr int RING = 6;       // rows L-5..L live in LDS
constexpr int CHUNKS = 66;    // quad 0 = left halo, 1..64 main, 65 = right halo
constexpr int STRIPW = 256;
constexpr int NSEG = H / HS;  // 32
constexpr int QD = 3;         // register staging queue depth

__device__ __forceinline__ void pin() {
    asm volatile("" ::: "memory");
    __builtin_amdgcn_sched_barrier(0);
}

// 4 f32 -> 4 f16 (RTZ, packed) in uint2: 2x v_cvt_pkrtz_f16_f32
__device__ __forceinline__ uint2 pack4h(float4 v) {
    auto a = __builtin_amdgcn_cvt_pkrtz(v.x, v.y);   // __fp16 ext_vector(2)
    auto b = __builtin_amdgcn_cvt_pkrtz(v.z, v.w);
    uint2 r;
    r.x = __builtin_bit_cast(unsigned, a);
    r.y = __builtin_bit_cast(unsigned, b);
    return r;
}

__device__ __forceinline__ void unp4(uint2 u, float* d) {
    __half2 h0 = __builtin_bit_cast(__half2, u.x);
    __half2 h1 = __builtin_bit_cast(__half2, u.y);
    float2 f0 = __half22float2(h0);
    float2 f1 = __half22float2(h1);
    d[0] = f0.x; d[1] = f0.y; d[2] = f1.x; d[3] = f1.y;
}

__device__ __forceinline__ void unp12(uint2 a, uint2 b, uint2 c, float* d) {
    unp4(a, d); unp4(b, d + 4); unp4(c, d + 8);
}

template <bool ATOMIC>
__global__ __launch_bounds__(64) void zncc_stream(const float* __restrict__ xg,
                                                  const float* __restrict__ yg,
                                                  float* __restrict__ outg) {
    __shared__ uint2 ring[2][RING][CHUNKS];   // 2*6*66*8 = 6336 B

    const int lane  = threadIdx.x;        // 0..63
    const int strip = blockIdx.x & 1;
    const int seg   = blockIdx.x >> 1;    // 0..31
    const int b     = blockIdx.y;
    const int ch    = blockIdx.z;
    const int o0    = seg * HS;

    const float* __restrict__ xp = xg + ((size_t)(b * Cn + ch)) * (H * W);
    const float* __restrict__ yp = yg + ((size_t)(b * Cn + ch)) * (H * W);
    float* __restrict__ outp =
        ATOMIC ? outg + (size_t)b * (H * W) + strip * STRIPW + lane * 4
               : outg + ((size_t)(b * Cn + ch)) * (H * W) + strip * STRIPW + lane * 4;

    const int m0 = strip * STRIPW + lane * 4;     // first output col
    // column-edge masks: only lane0/strip0 (left) and lane63/strip1 (right) clamp
    const float mA = (strip == 0 && lane == 0)  ? 0.f : 1.f;
    const float mC = (strip == 1 && lane == 63) ? 0.f : 1.f;

    float pm[8];
#pragma unroll
    for (int i = 0; i < 8; ++i) {
        int col = m0 - 2 + i;
        pm[i] = (col >= 0 && col < W) ? 1.f : 0.f;
    }

    // staging addresses
    const int sMain = strip * STRIPW + lane * 4;             // main quad src elem
    const int hoff  = lane ? (strip ? 508 : 256)             // right halo src
                           : (strip ? 252 : 0);              // left  halo src (clamped)
    const int hIdx  = lane ? 65 : 0;                         // halo quad in slot
    const bool hal  = lane < 2;

    // 3-deep register staging queue (rows L, L+1, L+2 in flight)
    float4 qmx[QD], qmy[QD], qhx[QD], qhy[QD];

    // prologue: load rows o0-4 .. o0-2 (clamped low) into queue slots 0..2
#pragma unroll
    for (int p = 0; p < QD; ++p) {
        const int rp = o0 - 4 + p;
        const int rc = rp < 0 ? 0 : rp;          // rp <= 494, no upper clamp
        const float* xr = xp + (size_t)rc * W;
        const float* yr = yp + (size_t)rc * W;
        qmx[p] = *(const float4*)(xr + sMain);
        qmy[p] = *(const float4*)(yr + sMain);
        if (hal) {
            qhx[p] = *(const float4*)(xr + hoff);
            qhy[p] = *(const float4*)(yr + hoff);
        }
    }

    float vsx[12], vsy[12];
    float qxx[5][4], qxy[5][4], qyy[5][4];
    float oxx[4], oxy[4], oyy[4];
#pragma unroll
    for (int i = 0; i < 12; ++i) { vsx[i] = 0.f; vsy[i] = 0.f; }
#pragma unroll
    for (int s = 0; s < 5; ++s)
#pragma unroll
        for (int j = 0; j < 4; ++j) { qxx[s][j] = 0.f; qxy[s][j] = 0.f; qyy[s][j] = 0.f; }
#pragma unroll
    for (int j = 0; j < 4; ++j) { oxx[j] = 0.f; oxy[j] = 0.f; oyy[j] = 0.f; }

    // iter k: row L = o0-4+k; queue slot k%QD holds row L (loaded at iter k-QD /
    // prologue); LDS slot k%6 receives row L this iter. vsum rows L-4..L;
    // products at V=L-2 (k>=4, slot (k-2)%6); subtract L-5 (k>=5, slot (k-5)%6,
    // freed right before iter k+1 overwrites it); output row o0+k-8 (k>=8).
#pragma unroll
    for (int k = 0; k < NITER; ++k) {
        const int L  = o0 - 4 + k;
        const int sL = k % RING;
        const int qs = k % QD;

        // (1) ds_write row L from reg queue (compiler emits the counted vmcnt
        //     for the loads issued QD iters ago — exact by dataflow, leaves
        //     the newer QD-1 iterations' loads in flight)
        ring[0][sL][lane + 1] = pack4h(qmx[qs]);
        ring[1][sL][lane + 1] = pack4h(qmy[qs]);
        if (hal) {
            ring[0][sL][hIdx] = pack4h(qhx[qs]);
            ring[1][sL][hIdx] = pack4h(qhy[qs]);
        }

        // (2) refill queue slot with row L+QD (clamped), issued before consume
        if (k < NITER - QD) {
            int rn = L + QD; rn = rn < 0 ? 0 : (rn > H - 1 ? H - 1 : rn);
            const float* xr = xp + (size_t)rn * W;
            const float* yr = yp + (size_t)rn * W;
            qmx[qs] = *(const float4*)(xr + sMain);
            qmy[qs] = *(const float4*)(yr + sMain);
            if (hal) {
                qhx[qs] = *(const float4*)(xr + hoff);
                qhy[qs] = *(const float4*)(yr + hoff);
            }
        }
        pin();   // keep the refill loads issued ahead of the consume block

        // (3) consume — batch ALL slot reads first (one lgkmcnt covers them),
        //     then convert + math. Row guards are branchless scalar 0/1 masks.
        const bool doSub = (k >= 5);
        const int sO = (k - 5 + RING) % RING;
        const int sV = (k - 2 + RING) % RING;
        const bool doV = (k >= 4) && (L - 2 >= 0) && (L - 2 < H);

        uint2 nxa = ring[0][sL][lane], nxb = ring[0][sL][lane + 1], nxc = ring[0][sL][lane + 2];
        uint2 nya = ring[1][sL][lane], nyb = ring[1][sL][lane + 1], nyc = ring[1][sL][lane + 2];
        uint2 oxa, oxb, oxc, oya, oyb, oyc;
        if (doSub) {
            oxa = ring[0][sO][lane]; oxb = ring[0][sO][lane + 1]; oxc = ring[0][sO][lane + 2];
            oya = ring[1][sO][lane]; oyb = ring[1][sO][lane + 1]; oyc = ring[1][sO][lane + 2];
        }
        uint2 cxa, cxb, cxc, cya, cyb, cyc;
        if (doV) {
            cxa = ring[0][sV][lane]; cxb = ring[0][sV][lane + 1]; cxc = ring[0][sV][lane + 2];
            cya = ring[1][sV][lane]; cyb = ring[1][sV][lane + 1]; cyc = ring[1][sV][lane + 2];
        }

        // add row L
        {
            const float rmN = (L >= 0 && L < H) ? 1.f : 0.f;
            const float cA = mA * rmN, cC = mC * rmN;
            float nx[12], ny[12];
            unp12(nxa, nxb, nxc, nx);
            unp12(nya, nyb, nyc, ny);
            vsx[0] = fmaf(nx[0], rmN, vsx[0]); vsx[1] = fmaf(nx[1], rmN, vsx[1]);
            vsx[2] = fmaf(nx[2], cA,  vsx[2]); vsx[3] = fmaf(nx[3], cA,  vsx[3]);
#pragma unroll
            for (int i = 4; i < 8; ++i) vsx[i] = fmaf(nx[i], rmN, vsx[i]);
            vsx[8] = fmaf(nx[8], cC, vsx[8]); vsx[9] = fmaf(nx[9], cC, vsx[9]);
            vsx[10] = fmaf(nx[10], rmN, vsx[10]); vsx[11] = fmaf(nx[11], rmN, vsx[11]);

            vsy[0] = fmaf(ny[0], rmN, vsy[0]); vsy[1] = fmaf(ny[1], rmN, vsy[1]);
            vsy[2] = fmaf(ny[2], cA,  vsy[2]); vsy[3] = fmaf(ny[3], cA,  vsy[3]);
#pragma unroll
            for (int i = 4; i < 8; ++i) vsy[i] = fmaf(ny[i], rmN, vsy[i]);
            vsy[8] = fmaf(ny[8], cC, vsy[8]); vsy[9] = fmaf(ny[9], cC, vsy[9]);
            vsy[10] = fmaf(ny[10], rmN, vsy[10]); vsy[11] = fmaf(ny[11], rmN, vsy[11]);
        }

        // subtract row L-5 (added at iter k-5; slot freed for iter k+1)
        if (doSub) {
            const int Lo = L - 5;
            const float rmO = (Lo >= 0) ? -1.f : 0.f;
            const float cA = mA * rmO, cC = mC * rmO;
            float ox[12], oy[12];
            unp12(oxa, oxb, oxc, ox);
            unp12(oya, oyb, oyc, oy);
            vsx[0] = fmaf(ox[0], rmO, vsx[0]); vsx[1] = fmaf(ox[1], rmO, vsx[1]);
            vsx[2] = fmaf(ox[2], cA,  vsx[2]); vsx[3] = fmaf(ox[3], cA,  vsx[3]);
#pragma unroll
            for (int i = 4; i < 8; ++i) vsx[i] = fmaf(ox[i], rmO, vsx[i]);
            vsx[8] = fmaf(ox[8], cC, vsx[8]); vsx[9] = fmaf(ox[9], cC, vsx[9]);
            vsx[10] = fmaf(ox[10], rmO, vsx[10]); vsx[11] = fmaf(ox[11], rmO, vsx[11]);

            vsy[0] = fmaf(oy[0], rmO, vsy[0]); vsy[1] = fmaf(oy[1], rmO, vsy[1]);
            vsy[2] = fmaf(oy[2], cA,  vsy[2]); vsy[3] = fmaf(oy[3], cA,  vsy[3]);
#pragma unroll
            for (int i = 4; i < 8; ++i) vsy[i] = fmaf(oy[i], rmO, vsy[i]);
            vsy[8] = fmaf(oy[8], cC, vsy[8]); vsy[9] = fmaf(oy[9], cC, vsy[9]);
            vsy[10] = fmaf(oy[10], rmO, vsy[10]); vsy[11] = fmaf(oy[11], rmO, vsy[11]);
        }

        if (k >= 4) {
            const int u = k % 5;   // hp queue slot (static after unroll)
#pragma unroll
            for (int j = 0; j < 4; ++j) {
                oxx[j] -= qxx[u][j]; oxy[j] -= qxy[u][j]; oyy[j] -= qyy[u][j];
            }
            if (doV) {
                float mx[8], my[8];
                mx[0] = vsx[0] + vsx[1] + vsx[2] + vsx[3] + vsx[4];
                my[0] = vsy[0] + vsy[1] + vsy[2] + vsy[3] + vsy[4];
#pragma unroll
                for (int i = 1; i < 8; ++i) {
                    mx[i] = mx[i - 1] - vsx[i - 1] + vsx[i + 4];
                    my[i] = my[i - 1] - vsy[i - 1] + vsy[i + 4];
                }
                float cx[12], cyv[12];
                unp12(cxa, cxb, cxc, cx);
                unp12(cya, cyb, cyc, cyv);

                float pxx[8], pxy[8], pyy[8];
#pragma unroll
                for (int i = 0; i < 8; ++i) {
                    float xc = (cx[i + 2]  - mx[i] * 0.04f) * pm[i];
                    float yc = (cyv[i + 2] - my[i] * 0.04f) * pm[i];
                    pxx[i] = xc * xc; pxy[i] = xc * yc; pyy[i] = yc * yc;
                }
                float h;
                h = pxx[0] + pxx[1] + pxx[2] + pxx[3] + pxx[4];
                qxx[u][0] = h; oxx[0] += h;
#pragma unroll
                for (int j = 1; j < 4; ++j) {
                    h = h - pxx[j - 1] + pxx[j + 4]; qxx[u][j] = h; oxx[j] += h;
                }
                h = pxy[0] + pxy[1] + pxy[2] + pxy[3] + pxy[4];
                qxy[u][0] = h; oxy[0] += h;
#pragma unroll
                for (int j = 1; j < 4; ++j) {
                    h = h - pxy[j - 1] + pxy[j + 4]; qxy[u][j] = h; oxy[j] += h;
                }
                h = pyy[0] + pyy[1] + pyy[2] + pyy[3] + pyy[4];
                qyy[u][0] = h; oyy[0] += h;
#pragma unroll
                for (int j = 1; j < 4; ++j) {
                    h = h - pyy[j - 1] + pyy[j + 4]; qyy[u][j] = h; oyy[j] += h;
                }
            } else {
                // padding row: products are zero
#pragma unroll
                for (int j = 0; j < 4; ++j) { qxx[u][j] = 0.f; qxy[u][j] = 0.f; qyy[u][j] = 0.f; }
            }

            if (k >= 8) {
                const int row = o0 + k - 8;
                float r[4];
#pragma unroll
                for (int j = 0; j < 4; ++j) {
                    // ncc = Sxy / (sqrt(Sxx*Syy) + 25e-8)
                    float rad = fmaxf(oxx[j] * oyy[j], 0.f);
                    float s = sqrtf(rad) + 2.5e-7f;
                    r[j] = oxy[j] * __builtin_amdgcn_rcpf(s);
                }
                if (ATOMIC) {
#pragma unroll
                    for (int j = 0; j < 4; ++j)
                        atomicAdd(outp + (size_t)row * W + j, r[j] * (1.f / 3.f));
                } else {
                    *(float4*)(outp + (size_t)row * W) =
                        make_float4(r[0], r[1], r[2], r[3]);
                }
            }
        }
    }
}

// out = (ch0 + ch1 + ch2) / 3 over the workspace planes
__global__ __launch_bounds__(256) void reduce3(const float4* __restrict__ ws,
                                               float4* __restrict__ o) {
    constexpr int PLANE4 = H * W / 4;           // 65536 float4 per plane
    constexpr int N4 = Bn * PLANE4;             // 1048576
    const float s = 1.f / 3.f;
    for (int g = blockIdx.x * 256 + threadIdx.x; g < N4; g += gridDim.x * 256) {
        const int bq = g >> 16;                 // PLANE4 == 1<<16
        const int r  = g & (PLANE4 - 1);
        const float4* p = ws + ((size_t)bq * 3) * PLANE4 + r;
        float4 a = p[0], c = p[PLANE4], d = p[2 * PLANE4];
        float4 v;
        v.x = (a.x + c.x + d.x) * s;
        v.y = (a.y + c.y + d.y) * s;
        v.z = (a.z + c.z + d.z) * s;
        v.w = (a.w + c.w + d.w) * s;
        o[g] = v;
    }
}

extern "C" void kernel_launch(void* const* d_in, const int* in_sizes, int n_in,
                              void* d_out, int out_size, void* d_ws, size_t ws_size,
                              hipStream_t stream) {
    const float* x = (const float*)d_in[0];
    const float* y = (const float*)d_in[1];
    float* out = (float*)d_out;
    dim3 grid(2 * NSEG, Bn, Cn);   // 64 x 16 x 3 = 3072 one-wave blocks

    const size_t needed = (size_t)Bn * Cn * H * W * sizeof(float);  // 50.3 MB
    if (d_ws != nullptr && ws_size >= needed) {
        zncc_stream<false><<<grid, 64, 0, stream>>>(x, y, (float*)d_ws);
        reduce3<<<2048, 256, 0, stream>>>((const float4*)d_ws, (float4*)out);
    } else {
        // harness pre-zeroes the output buffer; atomics accumulate on top
        zncc_stream<true><<<grid, 64, 0, stream>>>(x, y, out);
    }
}